// Round 16
// baseline (22473.442 us; speedup 1.0000x reference)
//
#include <hip/hip_runtime.h>

// Farthest point sampling, B=32, N=32768, npoint=4096.
// R16: 8 blocks/batch (grid=256 = all CUs), 4 pts/thread ALL in registers
// (px/py/pz/dist = 16 floats -> 64-reg class, no AGPR copies, no coord LDS).
// Cross-block agree per step: fresh 8B slot per (step,block); leader
// release-stores packed key (f32bits(dist)<<32 | ~idx); lanes 0-7 of wave 0
// acquire-poll the batch's 8 slots IN PARALLEL (one L2 round per iteration
// regardless of fan-in); 3-stage u64 max shuffle combine; ties -> smaller
// global index (numpy first-occurrence). Partners all == bid (mod 8) ->
// same XCD -> local-L2 polls. Winner=max -> replay-deterministic; slots
// zeroed by captured hipMemsetAsync. 256 blocks co-resident (1/CU).
// In-block: wave butterfly + 3-slot rotating LDS atomicMax (R12 proven).
// PASSING arithmetic (R6, bit-exact): d = fmaf(dz,dz, fmaf(dx,dx, dy*dy)),
// contract(off), fminf chain, ascending-index strict-> argmax.
// Output float32: [B*NPOINT] idx, [B*NPOINT*3] coords.

#define BATCH  32
#define NPTS   32768
#define NPOINT 4096
#define NT     1024

#define NSUB    8                      // blocks per batch
#define NBLKTOT (BATCH * NSUB)         // 256
#define PPB     (NPTS / NSUB)          // 4096 points per block
#define NPT     (PPB / NT)             // 4 points per thread
#define WS_N8   ((size_t)NPOINT * NBLKTOT * 8)   // 8 MB

__global__ __launch_bounds__(NT, 1) void fps8(
    const float* __restrict__ xyz,
    float* __restrict__ out_idx,
    float* __restrict__ out_xyz,
    unsigned long long* __restrict__ ex)   // [NPOINT][NBLKTOT], zeroed
{
#pragma clang fp contract(off)
    const int bid = blockIdx.x;
    const int g   = bid & (BATCH - 1);   // batch
    const int j   = bid >> 5;            // sub-block 0..7 (same XCD family)
    const int tid = threadIdx.x;
    const float* base = xyz + (size_t)g * NPTS * 3;
    const int goff = j * PPB;

    float px[NPT], py[NPT], pz[NPT], dist[NPT];
#pragma unroll
    for (int i = 0; i < NPT; ++i) {
        const int gg = goff + i * NT + tid;
        px[i] = base[gg * 3 + 0];
        py[i] = base[gg * 3 + 1];
        pz[i] = base[gg * 3 + 2];
        dist[i] = 1e10f;
    }

    __shared__ unsigned long long s_key[3];
    __shared__ int s_w;
    if (tid == 0) { s_key[0] = 0ull; s_key[1] = 0ull; s_key[2] = 0ull; }
    __syncthreads();

    int w = 1;   // RAN=False seed
    int p = 0;   // rotating slot index k%3

    for (int k = 0; k < NPOINT; ++k) {
        // Broadcast centroid (same addr across lanes -> one L2 transaction).
        const float cx = base[w * 3 + 0];
        const float cy = base[w * 3 + 1];
        const float cz = base[w * 3 + 2];
        if (j == 0 && tid == 0) {
            out_idx[(size_t)g * NPOINT + k] = (float)w;
            float* o = out_xyz + ((size_t)g * NPOINT + k) * 3;
            o[0] = cx; o[1] = cy; o[2] = cz;
        }
        if (k == NPOINT - 1) break;

        // Distance update + first-occurrence argmax over my 4 points
        // (local i ascends with global index -> strict > keeps first max).
        float best = -1.0f;
        int   li   = 7;
#pragma unroll
        for (int i = 0; i < NPT; ++i) {
            const float dx = px[i] - cx;
            const float dy = py[i] - cy;
            const float dz = pz[i] - cz;
            const float d  = fmaf(dz, dz, fmaf(dx, dx, dy * dy));
            const float nd = fminf(dist[i], d);
            dist[i] = nd;
            if (nd > best) { best = nd; li = i; }
        }
        int bi = goff + li * NT + tid;

        // Wave (64-lane) butterfly argmax; ties -> smaller index.
#pragma unroll
        for (int off = 1; off < 64; off <<= 1) {
            const float ov = __shfl_xor(best, off, 64);
            const int   oi = __shfl_xor(bi,   off, 64);
            if (ov > best || (ov == best && oi < bi)) { best = ov; bi = oi; }
        }

        // 16 wave leaders -> LDS atomicMax on packed key, slot p = k%3.
        if ((tid & 63) == 0) {
            const unsigned long long myk =
                ((unsigned long long)__float_as_uint(best) << 32) |
                (unsigned int)(~bi);
            atomicMax(&s_key[p], myk);
        }
        __syncthreads();                   // B1: block winner in s_key[p]

        // tid0: publish own block key (release, fresh slot).
        unsigned long long* row = ex + (size_t)k * NBLKTOT;
        if (tid == 0) {
            __hip_atomic_store(&row[bid], s_key[p], __ATOMIC_RELEASE,
                               __HIP_MEMORY_SCOPE_AGENT);
            const int pn2 = (p >= 1) ? (p - 1) : 2;   // reset slot for k+2
            s_key[pn2] = 0ull;
        }
        // Lanes 0-7 of wave 0: parallel acquire-poll of the 8 batch slots
        // (key always nonzero: low word = ~idx >= ~32767).
        unsigned long long pk = 0ull;
        if (tid < 8) {
            const unsigned long long* sl = &row[g + (tid << 5)];
            do {
                pk = __hip_atomic_load(sl, __ATOMIC_ACQUIRE,
                                       __HIP_MEMORY_SCOPE_AGENT);
            } while (pk == 0ull);
        }
        if (tid < 64) {   // 3-stage max combine across lanes 0-7
#pragma unroll
            for (int off = 1; off < 8; off <<= 1) {
                const unsigned long long o = __shfl_xor(pk, off, 64);
                if (o > pk) pk = o;
            }
            if (tid == 0) s_w = (int)(~(unsigned int)pk);
        }
        __syncthreads();                   // B2: combined winner ready
        w = s_w;
        p = (p == 2) ? 0 : (p + 1);
    }
}

// ---------- fallback 1 (R15 pair, passing 11.25ms): ws >= 2MB ----------
#define HALF   16384
#define PNCH   8
#define P_SMEM (HALF * 4 + 64)
#define WS_PAIR ((size_t)NPOINT * 64 * 8)

__global__ __launch_bounds__(NT, 1) void fps_pair(
    const float* __restrict__ xyz, float* __restrict__ out_idx,
    float* __restrict__ out_xyz, unsigned long long* __restrict__ ex)
{
#pragma clang fp contract(off)
    extern __shared__ char smem[];
    float* pz_lds = (float*)smem;
    unsigned long long* s_key = (unsigned long long*)(smem + HALF * 4);
    int* s_w = (int*)(smem + HALF * 4 + 24);
    const int bid = blockIdx.x;
    const int g = bid & (BATCH - 1), h = bid >> 5, tid = threadIdx.x;
    const float* base = xyz + (size_t)g * NPTS * 3;
    const int goff = h * HALF;
    float px[PNCH * 2], py[PNCH * 2], dist[PNCH * 2];
#pragma unroll
    for (int c = 0; c < PNCH; ++c)
#pragma unroll
        for (int j2 = 0; j2 < 2; ++j2) {
            const int i = c * 2 + j2, gl = c * 2048 + 2 * tid + j2;
            px[i] = base[(goff + gl) * 3 + 0];
            py[i] = base[(goff + gl) * 3 + 1];
            pz_lds[gl] = base[(goff + gl) * 3 + 2];
            dist[i] = 1e10f;
        }
    if (tid == 0) { s_key[0] = 0ull; s_key[1] = 0ull; s_key[2] = 0ull; }
    __syncthreads();
    int w = 1, p = 0;
    for (int k = 0; k < NPOINT; ++k) {
        const float cx = base[w * 3 + 0], cy = base[w * 3 + 1],
                    cz = base[w * 3 + 2];
        if (h == 0 && tid == 0) {
            out_idx[(size_t)g * NPOINT + k] = (float)w;
            float* o = out_xyz + ((size_t)g * NPOINT + k) * 3;
            o[0] = cx; o[1] = cy; o[2] = cz;
        }
        if (k == NPOINT - 1) break;
        float best = -1.0f; int lc = 31;
#pragma unroll
        for (int c = 0; c < PNCH; ++c) {
            const float2 zz = *(const float2*)&pz_lds[c * 2048 + 2 * tid];
            const float pzv[2] = { zz.x, zz.y };
#pragma unroll
            for (int j2 = 0; j2 < 2; ++j2) {
                const int i = c * 2 + j2;
                const float dx = px[i] - cx, dy = py[i] - cy,
                            dz = pzv[j2] - cz;
                const float d  = fmaf(dz, dz, fmaf(dx, dx, dy * dy));
                const float nd = fminf(dist[i], d);
                dist[i] = nd;
                if (nd > best) { best = nd; lc = 2 * c + j2; }
            }
        }
        int bi = goff + (lc >> 1) * 2048 + 2 * tid + (lc & 1);
#pragma unroll
        for (int off = 1; off < 64; off <<= 1) {
            const float ov = __shfl_xor(best, off, 64);
            const int   oi = __shfl_xor(bi,   off, 64);
            if (ov > best || (ov == best && oi < bi)) { best = ov; bi = oi; }
        }
        if ((tid & 63) == 0) {
            const unsigned long long myk =
                ((unsigned long long)__float_as_uint(best) << 32) |
                (unsigned int)(~bi);
            atomicMax(&s_key[p], myk);
        }
        __syncthreads();
        if (tid == 0) {
            const unsigned long long kk = s_key[p];
            const int pn2 = (p >= 1) ? (p - 1) : 2;
            s_key[pn2] = 0ull;
            unsigned long long* slot = ex + (size_t)k * 64;
            __hip_atomic_store(&slot[bid], kk, __ATOMIC_RELEASE,
                               __HIP_MEMORY_SCOPE_AGENT);
            unsigned long long pk;
            do {
                pk = __hip_atomic_load(&slot[bid ^ 32], __ATOMIC_ACQUIRE,
                                       __HIP_MEMORY_SCOPE_AGENT);
            } while (pk == 0ull);
            const unsigned long long win = (kk > pk) ? kk : pk;
            *s_w = (int)(~(unsigned int)win);
        }
        __syncthreads();
        w = *s_w;
        p = (p == 2) ? 0 : (p + 1);
    }
}

// ---------- fallback 2 (R10/R12 single, passing 12.7ms) ----------
#define FB_NCH 16
#define FB_SMEM (NPTS * 4 + 32)

__global__ __launch_bounds__(NT, 1) void fps_single(
    const float* __restrict__ xyz, float* __restrict__ out_idx,
    float* __restrict__ out_xyz)
{
#pragma clang fp contract(off)
    extern __shared__ char smem[];
    float* pz_lds = (float*)smem;
    unsigned long long* s_key = (unsigned long long*)(smem + NPTS * 4);
    const int b = blockIdx.x, tid = threadIdx.x;
    const float* base = xyz + (size_t)b * NPTS * 3;
    float px[FB_NCH * 2], py[FB_NCH * 2], dist[FB_NCH * 2];
#pragma unroll
    for (int c = 0; c < FB_NCH; ++c)
#pragma unroll
        for (int j2 = 0; j2 < 2; ++j2) {
            const int i = c * 2 + j2, gg = c * 2048 + 2 * tid + j2;
            px[i] = base[gg * 3 + 0]; py[i] = base[gg * 3 + 1];
            pz_lds[gg] = base[gg * 3 + 2]; dist[i] = 1e10f;
        }
    if (tid == 0) { s_key[0] = 0ull; s_key[1] = 0ull; s_key[2] = 0ull; }
    __syncthreads();
    int w = 1, p = 0;
    for (int k = 0; k < NPOINT; ++k) {
        const float cx = base[w * 3 + 0], cy = base[w * 3 + 1],
                    cz = base[w * 3 + 2];
        if (tid == 0) {
            out_idx[(size_t)b * NPOINT + k] = (float)w;
            float* o = out_xyz + ((size_t)b * NPOINT + k) * 3;
            o[0] = cx; o[1] = cy; o[2] = cz;
        }
        float best = -1.0f; int lc = 63;
#pragma unroll
        for (int c = 0; c < FB_NCH; ++c) {
            const float2 zz = *(const float2*)&pz_lds[c * 2048 + 2 * tid];
            const float pzv[2] = { zz.x, zz.y };
#pragma unroll
            for (int j2 = 0; j2 < 2; ++j2) {
                const int i = c * 2 + j2;
                const float dx = px[i] - cx, dy = py[i] - cy,
                            dz = pzv[j2] - cz;
                const float d  = fmaf(dz, dz, fmaf(dx, dx, dy * dy));
                const float nd = fminf(dist[i], d);
                dist[i] = nd;
                if (nd > best) { best = nd; lc = 2 * c + j2; }
            }
        }
        int bi = (lc >> 1) * 2048 + 2 * tid + (lc & 1);
#pragma unroll
        for (int off = 1; off < 64; off <<= 1) {
            const float ov = __shfl_xor(best, off, 64);
            const int   oi = __shfl_xor(bi,   off, 64);
            if (ov > best || (ov == best && oi < bi)) { best = ov; bi = oi; }
        }
        if ((tid & 63) == 0) {
            const unsigned long long myk =
                ((unsigned long long)__float_as_uint(best) << 32) |
                (unsigned int)(~bi);
            atomicMax(&s_key[p], myk);
        }
        __syncthreads();
        const unsigned long long kk = s_key[p];
        const int pn2 = (p >= 1) ? (p - 1) : 2;
        if (tid == 0) s_key[pn2] = 0ull;
        w = (int)(~(unsigned int)kk);
        p = (p == 2) ? 0 : (p + 1);
    }
}

extern "C" void kernel_launch(void* const* d_in, const int* in_sizes, int n_in,
                              void* d_out, int out_size, void* d_ws, size_t ws_size,
                              hipStream_t stream) {
    const float* xyz = (const float*)d_in[0];
    float* out = (float*)d_out;
    float* out_idx = out;
    float* out_xyz = out + (size_t)BATCH * NPOINT;

    if (ws_size >= WS_N8) {
        unsigned long long* ex = (unsigned long long*)d_ws;
        hipMemsetAsync(d_ws, 0, WS_N8, stream);
        fps8<<<NBLKTOT, NT, 0, stream>>>(xyz, out_idx, out_xyz, ex);
    } else if (ws_size >= WS_PAIR) {
        unsigned long long* ex = (unsigned long long*)d_ws;
        hipMemsetAsync(d_ws, 0, WS_PAIR, stream);
        (void)hipFuncSetAttribute((const void*)fps_pair,
                                  hipFuncAttributeMaxDynamicSharedMemorySize,
                                  P_SMEM);
        fps_pair<<<64, NT, P_SMEM, stream>>>(xyz, out_idx, out_xyz, ex);
    } else {
        (void)hipFuncSetAttribute((const void*)fps_single,
                                  hipFuncAttributeMaxDynamicSharedMemorySize,
                                  FB_SMEM);
        fps_single<<<BATCH, NT, FB_SMEM, stream>>>(xyz, out_idx, out_xyz);
    }
}

// Round 17
// 12490.362 us; speedup vs baseline: 1.7993x; 1.7993x over previous
//
#include <hip/hip_runtime.h>

// Farthest point sampling, B=32, N=32768, npoint=4096.
// R17: single block/batch (R10/R12 topology) + STATIC 128KB LDS for z.
// Theory: the register allocator targets max ACHIEVABLE occupancy. With
// dynamic LDS (invisible at compile time) or small static LDS (56KB, R12),
// it assumes 2+ blocks/CU -> 8 waves/SIMD -> 64-arch-VGPR class, parking
// the ~96-float px/py/dist state in AGPRs (v_accvgpr copies ~2.5x VALU
// issue -> stuck at ~12.7ms). A VISIBLE 128KB static LDS forces the
// backend's own occupancy calc to 1 block/CU -> 4 waves/SIMD -> per-wave
// budget 512 -> need-driven ~116 arch VGPRs, no copies.
// (Cross-block alternatives measured: pair sync +1.4us/step, 8-way
// +4.5us/step through L3 coherence point -> single-block wins.)
//  - pair ownership g = c*2048 + 2*tid + j, ds_read_b64 (R10 proven).
//  - 3-slot rotating LDS atomicMax reduce, ONE barrier/step (R12 proven):
//    leaders atomicMax packed key (f32bits(dist)<<32 | ~idx) into
//    s_key[k%3]; barrier; all read; tid0 resets slot (k+2)%3 (ordered by
//    the next step's barrier). Ties -> smaller idx = numpy first-occurrence.
// PASSING arithmetic (R6, bit-exact): d = fmaf(dz,dz, fmaf(dx,dx, dy*dy)),
// contract(off), fminf chain, ascending-index strict-> argmax.
// Output float32: [B*NPOINT] idx, [B*NPOINT*3] coords.

#define BATCH  32
#define NPTS   32768
#define NPOINT 4096
#define NT     1024
#define NCH    16            // chunks of 2: 32 points per thread

__global__ __launch_bounds__(NT, 1) void fps_kernel(
    const float* __restrict__ xyz,   // [B, N, 3] float32
    float* __restrict__ out_idx,     // [B, NPOINT]
    float* __restrict__ out_xyz)     // [B, NPOINT, 3]
{
#pragma clang fp contract(off)
    __shared__ float pz_lds[NPTS];               // 128 KB STATIC (visible!)
    __shared__ unsigned long long s_key[3];

    const int b   = blockIdx.x;
    const int tid = threadIdx.x;
    const float* base = xyz + (size_t)b * NPTS * 3;

    float px[NCH * 2], py[NCH * 2], dist[NCH * 2];
#pragma unroll
    for (int c = 0; c < NCH; ++c) {
#pragma unroll
        for (int j = 0; j < 2; ++j) {
            const int i = c * 2 + j;
            const int g = c * 2048 + 2 * tid + j;
            px[i] = base[g * 3 + 0];
            py[i] = base[g * 3 + 1];
            pz_lds[g] = base[g * 3 + 2];
            dist[i] = 1e10f;
        }
    }
    if (tid == 0) { s_key[0] = 0ull; s_key[1] = 0ull; s_key[2] = 0ull; }
    __syncthreads();                       // pz_lds + slots ready

    int w = 1;   // RAN=False seed
    int p = 0;   // rotating slot index k%3

    for (int k = 0; k < NPOINT; ++k) {
        // Broadcast centroid from global (same addr across lanes, L2-hot).
        const float cx = base[w * 3 + 0];
        const float cy = base[w * 3 + 1];
        const float cz = base[w * 3 + 2];
        if (tid == 0) {
            out_idx[(size_t)b * NPOINT + k] = (float)w;
            float* o = out_xyz + ((size_t)b * NPOINT + k) * 3;
            o[0] = cx; o[1] = cy; o[2] = cz;
        }

        // Distance update + first-occurrence argmax (per-thread indices
        // ascend with c,j -> strict > keeps the first max).
        float best = -1.0f;
        int   lc   = 63;
#pragma unroll
        for (int c = 0; c < NCH; ++c) {
            const float2 zz = *(const float2*)&pz_lds[c * 2048 + 2 * tid];
            const float pzv[2] = { zz.x, zz.y };
#pragma unroll
            for (int j = 0; j < 2; ++j) {
                const int i = c * 2 + j;
                const float dx = px[i] - cx;
                const float dy = py[i] - cy;
                const float dz = pzv[j] - cz;
                const float d  = fmaf(dz, dz, fmaf(dx, dx, dy * dy));
                const float nd = fminf(dist[i], d);
                dist[i] = nd;
                if (nd > best) { best = nd; lc = 2 * c + j; }
            }
        }
        // Reconstruct global index: g = (lc>>1)*2048 + 2*tid + (lc&1).
        int bi = (lc >> 1) * 2048 + 2 * tid + (lc & 1);

        // Wave (64-lane) butterfly argmax; ties -> smaller index.
#pragma unroll
        for (int off = 1; off < 64; off <<= 1) {
            const float ov = __shfl_xor(best, off, 64);
            const int   oi = __shfl_xor(bi,   off, 64);
            if (ov > best || (ov == best && oi < bi)) { best = ov; bi = oi; }
        }

        // 16 wave leaders -> LDS atomicMax on packed key, slot p = k%3.
        if ((tid & 63) == 0) {
            const unsigned long long myk =
                ((unsigned long long)__float_as_uint(best) << 32) |
                (unsigned int)(~bi);
            atomicMax(&s_key[p], myk);
        }
        __syncthreads();                   // winner published
        const unsigned long long kk = s_key[p];
        // Reset slot for step k+2 (next step's barrier orders this write
        // before that step's atomicMax; its readers finished at step k-1).
        const int pn2 = (p >= 1) ? (p - 1) : 2;   // (k+2)%3
        if (tid == 0) s_key[pn2] = 0ull;
        w = (int)(~(unsigned int)kk);      // low word = ~idx
        p = (p == 2) ? 0 : (p + 1);
    }
}

extern "C" void kernel_launch(void* const* d_in, const int* in_sizes, int n_in,
                              void* d_out, int out_size, void* d_ws, size_t ws_size,
                              hipStream_t stream) {
    const float* xyz = (const float*)d_in[0];
    float* out = (float*)d_out;
    float* out_idx = out;                              // B*NPOINT floats
    float* out_xyz = out + (size_t)BATCH * NPOINT;     // B*NPOINT*3 floats

    fps_kernel<<<BATCH, NT, 0, stream>>>(xyz, out_idx, out_xyz);
}

// Round 18
// 8764.489 us; speedup vs baseline: 2.5641x; 1.4251x over previous
//
#include <hip/hip_runtime.h>

// Farthest point sampling, B=32, N=32768, npoint=4096.
// R18 = R17 base (1 block/batch, static 128KB LDS for z, pair ds_read_b64)
// plus:
//  (1) __attribute__((amdgpu_num_vgpr(128))): DIRECT per-wave VGPR budget.
//      Every indirect lever (launch_bounds, waves_per_eu, static/dynamic
//      LDS) left the heuristic budget at 64 arch VGPRs and parked the
//      ~96-float px/py/dist state in AGPRs (copy traffic = the measured
//      ~2.5x VALU issue inflation). 128 regs keeps 4 waves/SIMD
//      (16 waves/CU) and fits the ~116-float live set.
//  (2) two-phase reduce: value-only butterfly (6 x {swizzle,max}) ->
//      leaders atomicMax 32-bit distance bits into s_val[k%3]; barrier;
//      threads with best==M atomicMin their first-achieving global index
//      into s_idx[k%3]; barrier. Numpy first-occurrence preserved:
//      per-thread lc is the strict-> first achiever, global argmax =
//      min index among candidates. tid0 resets slot (k+2)%3 after B2
//      (ordered before its next use by the intervening barriers).
// PASSING arithmetic (R6, bit-exact): d = fmaf(dz,dz, fmaf(dx,dx, dy*dy)),
// contract(off), fminf chain, ascending-index strict-> argmax.
// Output float32: [B*NPOINT] idx, [B*NPOINT*3] coords.

#define BATCH  32
#define NPTS   32768
#define NPOINT 4096
#define NT     1024
#define NCH    16            // chunks of 2: 32 points per thread

__global__ __launch_bounds__(NT, 1)
__attribute__((amdgpu_num_vgpr(128)))
void fps_kernel(
    const float* __restrict__ xyz,   // [B, N, 3] float32
    float* __restrict__ out_idx,     // [B, NPOINT]
    float* __restrict__ out_xyz)     // [B, NPOINT, 3]
{
#pragma clang fp contract(off)
    __shared__ float pz_lds[NPTS];               // 128 KB static
    __shared__ unsigned int s_val[3];            // dist bits (f32>=0 monotone)
    __shared__ int s_idx[3];                     // winning global index

    const int b   = blockIdx.x;
    const int tid = threadIdx.x;
    const float* base = xyz + (size_t)b * NPTS * 3;

    float px[NCH * 2], py[NCH * 2], dist[NCH * 2];
#pragma unroll
    for (int c = 0; c < NCH; ++c) {
#pragma unroll
        for (int j = 0; j < 2; ++j) {
            const int i = c * 2 + j;
            const int g = c * 2048 + 2 * tid + j;
            px[i] = base[g * 3 + 0];
            py[i] = base[g * 3 + 1];
            pz_lds[g] = base[g * 3 + 2];
            dist[i] = 1e10f;
        }
    }
    if (tid == 0) {
        s_val[0] = 0u; s_val[1] = 0u; s_val[2] = 0u;
        s_idx[0] = 0x7fffffff; s_idx[1] = 0x7fffffff; s_idx[2] = 0x7fffffff;
    }
    __syncthreads();                       // pz_lds + slots ready

    int w = 1;   // RAN=False seed
    int p = 0;   // rotating slot index k%3

    for (int k = 0; k < NPOINT; ++k) {
        // Broadcast centroid from global (same addr across lanes, L2-hot).
        const float cx = base[w * 3 + 0];
        const float cy = base[w * 3 + 1];
        const float cz = base[w * 3 + 2];
        if (tid == 0) {
            out_idx[(size_t)b * NPOINT + k] = (float)w;
            float* o = out_xyz + ((size_t)b * NPOINT + k) * 3;
            o[0] = cx; o[1] = cy; o[2] = cz;
        }

        // Distance update + per-thread first-occurrence argmax.
        float best = -1.0f;
        int   lc   = 63;
#pragma unroll
        for (int c = 0; c < NCH; ++c) {
            const float2 zz = *(const float2*)&pz_lds[c * 2048 + 2 * tid];
            const float pzv[2] = { zz.x, zz.y };
#pragma unroll
            for (int j = 0; j < 2; ++j) {
                const int i = c * 2 + j;
                const float dx = px[i] - cx;
                const float dy = py[i] - cy;
                const float dz = pzv[j] - cz;
                const float d  = fmaf(dz, dz, fmaf(dx, dx, dy * dy));
                const float nd = fminf(dist[i], d);
                dist[i] = nd;
                if (nd > best) { best = nd; lc = 2 * c + j; }
            }
        }

        // Phase A: value-only wave butterfly max (cheap stages).
        float m = best;
#pragma unroll
        for (int off = 1; off < 64; off <<= 1)
            m = fmaxf(m, __shfl_xor(m, off, 64));
        if ((tid & 63) == 0)
            atomicMax(&s_val[p], __float_as_uint(m));
        __syncthreads();                   // B1: block max value known
        const float M = __uint_as_float(s_val[p]);

        // Phase B: candidates (best==M; dist>=0 so bits compare cleanly)
        // publish their FIRST-achieving global index; min = numpy argmax.
        if (best == M) {
            const int bi = (lc >> 1) * 2048 + 2 * tid + (lc & 1);
            atomicMin(&s_idx[p], bi);
        }
        __syncthreads();                   // B2: winning index known
        w = s_idx[p];
        // Reset slot for step k+2 (B1/B2 of step k+1 order this write
        // before that slot's next atomics; its readers finished at k-1).
        const int pn2 = (p >= 1) ? (p - 1) : 2;   // (k+2)%3
        if (tid == 0) { s_val[pn2] = 0u; s_idx[pn2] = 0x7fffffff; }
        p = (p == 2) ? 0 : (p + 1);
    }
}

extern "C" void kernel_launch(void* const* d_in, const int* in_sizes, int n_in,
                              void* d_out, int out_size, void* d_ws, size_t ws_size,
                              hipStream_t stream) {
    const float* xyz = (const float*)d_in[0];
    float* out = (float*)d_out;
    float* out_idx = out;                              // B*NPOINT floats
    float* out_xyz = out + (size_t)BATCH * NPOINT;     // B*NPOINT*3 floats

    fps_kernel<<<BATCH, NT, 0, stream>>>(xyz, out_idx, out_xyz);
}